// Round 3
// baseline (292.183 us; speedup 1.0000x reference)
//
#include <hip/hip_runtime.h>
#include <stdint.h>
#include <math.h>

// ---- problem constants ----
#define NB 32
#define NH 256
#define NW 256
#define HW 65536
#define NJ 8
#define NCHAN 9           // 1 det channel + 8 joint channels per batch
#define NCH 288           // NB * NCHAN
#define NPART 4           // quarter-channel decomposition (64 rows each)
#define QROWS 64
#define TOPK 100
#define THRESH_C 0.1f
#define NEG_C (-10000.0f)
#define CAPS_Q 2432       // LDS survivor cap per quarter; mean ~1820, sigma ~40 -> mu+15sigma
#define NSLOT_Q 10        // ceil(CAPS_Q / 256) register key slots per thread

// ---- output layout (float offsets), concat of reference return tuple ----
#define OUT_BBOX  0       // (32,100,4)   12800
#define OUT_SCORE 12800   // (32,100,1)    3200
#define OUT_KPS   16000   // (32,100,16)  51200
#define OUT_CLS   67200   // (32,100,1)    3200
#define OUT_SCALE 70400   // (32,100,3)    9600
#define OUT_DISP  80000   // (32,100,16)  51200
#define OUT_HEAT  131200  // (32,100,16)  51200
// total 182400

// monotone float->uint key (order-preserving, incl. negatives)
__device__ __forceinline__ uint32_t flip_key(uint32_t b) {
    return (b & 0x80000000u) ? ~b : (b | 0x80000000u);
}
__device__ __forceinline__ float key_to_float(uint32_t k) {
    uint32_t b = (k & 0x80000000u) ? (k & 0x7FFFFFFFu) : ~k;
    return __uint_as_float(b);
}
__device__ __forceinline__ float sigmoidf_(float x) {
    return 1.0f / (1.0f + expf(-x));
}

// Fused NMS + survivor compaction + exact per-quarter top-K.
// 1152 blocks (288 channels x 4 quarter-slabs of 64 rows), 256 threads = 4
// waves x 16 rows. Why quarters: 288 blocks on 256 CUs left 32 CUs running 2
// full channels serially (worst-CU = 2.0 channel-equivalents); 1152 blocks at
// 5 resident/CU gives worst-CU 1.25. Exactness: channel top-100 is a subset of
// the union of quarter top-100s; decode_tail rank-merges the 4 sorted lists.
// Composite key u64 = (flip(raw)<<32) | (0xFFFFFFFF - pixel_idx): value desc,
// index asc -- matches jax.lax.top_k stable tie order.
__global__ __launch_bounds__(256, 5) void nms_topk(
        const float* __restrict__ hm, const float* __restrict__ hm_hp,
        uint64_t* __restrict__ part_keys) {
    int bid = blockIdx.x;
    int ch = bid >> 2, q = bid & 3;
    int b = ch / NCHAN, c = ch % NCHAN;
    const float* __restrict__ src = (c == 0)
        ? (hm + (size_t)b * HW)
        : (hm_hp + ((size_t)b * NJ + (c - 1)) * HW);

    __shared__ uint32_t skey[CAPS_Q];    // 9728 B survivor keys (flip-float)
    __shared__ uint16_t sidx[CAPS_Q];    // 4864 B survivor pixel index (y*256+x)
    __shared__ uint32_t hist[4][257];    // 4112 B one copy per wave, 257-pitch de-aliases banks
    __shared__ uint2 cand[TOPK];         // 800 B
    __shared__ uint32_t tieIdx[256];     // 1024 B
    __shared__ uint64_t keys[128];       // 1024 B
    __shared__ int blk_cnt;
    __shared__ int sKrem;
    __shared__ uint32_t sMask, sPref;
    __shared__ int gcnt, tcnt;
    // total ~21.7 KB -> 5 blocks/CU resident (launch_bounds(256,5): VGPR<=102)

    if (threadIdx.x == 0) blk_cnt = 0;
    __syncthreads();

    // ---- phase 1: streamed NMS (RAW space, monotone-equiv to sigmoid) ----
    // 4 waves x 16 rows, depth-2 rolling prefetch. Slab halo rows (y-1 below
    // row 64q, y+1 above 64q+63) are plain clamped global reads.
    int w    = threadIdx.x >> 6;        // wave 0..3: rows [64q+16w, +16)
    int lane = threadIdx.x & 63;        // 64 col-groups of 4 px (float4)
    int y0 = q * QROWS + w * 16;
    int xb = lane * 4;
    const float4* __restrict__ rbase = (const float4*)src;  // row r: rbase[r*64+lane]

    float4 prev = rbase[(size_t)((y0 > 0) ? y0 - 1 : 0) * 64 + lane];
    float4 cur  = rbase[(size_t)y0 * 64 + lane];
    float4 nxt  = rbase[(size_t)(y0 + 1) * 64 + lane];   // y0 <= 240 -> <= 241
    float4 nxt2 = rbase[(size_t)(y0 + 2) * 64 + lane];   // <= 242

    for (int y = y0; y < y0 + 16; ++y) {
        int ypf = y + 3; if (ypf > NH - 1) ypf = NH - 1;
        float4 nxt3 = rbase[(size_t)ypf * 64 + lane];    // prefetch (used in 2 iters)

        float4 nb;                                        // row y+1 (clamped)
        if (y < NH - 1) nb = nxt; else nb = cur;

        // vertical max per column
        float vm0 = fmaxf(fmaxf(prev.x, cur.x), nb.x);
        float vm1 = fmaxf(fmaxf(prev.y, cur.y), nb.y);
        float vm2 = fmaxf(fmaxf(prev.z, cur.z), nb.z);
        float vm3 = fmaxf(fmaxf(prev.w, cur.w), nb.w);

        // horizontal edges from neighbor lanes (one wave == one row)
        float fromLeft  = __shfl(vm3, (lane + 63) & 63);
        float fromRight = __shfl(vm0, (lane + 1) & 63);
        if (lane == 0)  fromLeft  = vm0;   // x=0 clamps to itself
        if (lane == 63) fromRight = vm3;   // x=255 clamps to itself

        float h0 = fmaxf(fromLeft, fmaxf(vm0, vm1));
        float h1 = fmaxf(vm0, fmaxf(vm1, vm2));
        float h2 = fmaxf(vm1, fmaxf(vm2, vm3));
        float h3 = fmaxf(vm2, fmaxf(vm3, fromRight));

        bool s0 = (cur.x >= h0), s1 = (cur.y >= h1);
        bool s2 = (cur.z >= h2), s3 = (cur.w >= h3);

        // ballot-ranked append (one LDS atomic per wave per row)
        uint64_t b0 = __ballot(s0), b1 = __ballot(s1);
        uint64_t b2 = __ballot(s2), b3 = __ballot(s3);
        int n0 = __popcll(b0), n1 = __popcll(b1);
        int n2 = __popcll(b2), n3 = __popcll(b3);
        int wtot = n0 + n1 + n2 + n3;
        uint64_t mlt = ((uint64_t)1 << lane) - 1;
        int r0 = __popcll(b0 & mlt);
        int r1 = n0 + __popcll(b1 & mlt);
        int r2 = n0 + n1 + __popcll(b2 & mlt);
        int r3 = n0 + n1 + n2 + __popcll(b3 & mlt);
        int wbase_l = 0;
        if (lane == 0) wbase_l = atomicAdd(&blk_cnt, wtot);
        int wbase = __shfl(wbase_l, 0);

        int rowoff = y * NW + xb;
        if (s0) { int o = wbase + r0; if (o < CAPS_Q) { skey[o] = flip_key(__float_as_uint(cur.x)); sidx[o] = (uint16_t)(rowoff + 0); } }
        if (s1) { int o = wbase + r1; if (o < CAPS_Q) { skey[o] = flip_key(__float_as_uint(cur.y)); sidx[o] = (uint16_t)(rowoff + 1); } }
        if (s2) { int o = wbase + r2; if (o < CAPS_Q) { skey[o] = flip_key(__float_as_uint(cur.z)); sidx[o] = (uint16_t)(rowoff + 2); } }
        if (s3) { int o = wbase + r3; if (o < CAPS_Q) { skey[o] = flip_key(__float_as_uint(cur.w)); sidx[o] = (uint16_t)(rowoff + 3); } }

        prev = cur; cur = nxt; nxt = nxt2; nxt2 = nxt3;
    }

    __syncthreads();
    int nl = min(blk_cnt, CAPS_Q);

    // stage keys into registers once (static slots, fully unrolled -> no scratch);
    // sentinel 0 never matches any predicate (T's top byte >= 0x80: top-100 of
    // ~1800 Gaussian survivors are positive -> flip_key >= 0x80000000 > 0)
    uint32_t kr[NSLOT_Q];
    #pragma unroll
    for (int s = 0; s < NSLOT_Q; ++s) {
        int i = threadIdx.x + (s << 8);
        kr[s] = (i < nl) ? skey[i] : 0u;
    }

    // ---- phase 2: byte-radix select of exact top-K threshold ----
    if (threadIdx.x == 0) { sKrem = TOPK; sMask = 0; sPref = 0; }
    int hc = threadIdx.x >> 6;           // histogram copy: one per wave
    for (int shift = 24; shift >= 0; shift -= 8) {
        for (int i = threadIdx.x; i < 4 * 256; i += 256) hist[i >> 8][i & 255] = 0;
        __syncthreads();
        uint32_t pm = sMask, pv = sPref;
        #pragma unroll
        for (int s = 0; s < NSLOT_Q; ++s) {
            int i = threadIdx.x + (s << 8);
            uint32_t vb = kr[s];
            if (i < nl && (vb & pm) == pv)
                atomicAdd(&hist[hc][(vb >> shift) & 0xFF], 1u);
        }
        __syncthreads();
        // wave-0 parallel threshold scan: merge 4 copies, shfl suffix-sum,
        // locate largest bin with suffix >= rem.
        if (threadIdx.x < 64) {
            int l = threadIdx.x;
            uint32_t h0 = hist[0][4*l+0] + hist[1][4*l+0] + hist[2][4*l+0] + hist[3][4*l+0];
            uint32_t h1 = hist[0][4*l+1] + hist[1][4*l+1] + hist[2][4*l+1] + hist[3][4*l+1];
            uint32_t h2 = hist[0][4*l+2] + hist[1][4*l+2] + hist[2][4*l+2] + hist[3][4*l+2];
            uint32_t h3 = hist[0][4*l+3] + hist[1][4*l+3] + hist[2][4*l+3] + hist[3][4*l+3];
            uint32_t loc = h0 + h1 + h2 + h3;
            uint32_t suf = loc;                    // suffix sum over lanes >= l
            #pragma unroll
            for (int d = 1; d < 64; d <<= 1) {
                uint32_t o = __shfl_down(suf, d, 64);
                suf += (l + d < 64) ? o : 0u;
            }
            uint32_t above = suf - loc;            // sum over lanes > l
            uint32_t rem = (uint32_t)sKrem;        // all lanes read before boundary lane writes
            if (suf >= rem && above < rem) {       // unique lane holds the boundary
                uint32_t S3 = above + h3;
                uint32_t S2 = S3 + h2;
                uint32_t S1 = S2 + h1;
                uint32_t S0 = S1 + h0;             // == suf
                int bin; uint32_t Sb, hb;
                if      (S3 >= rem) { bin = 4*l+3; Sb = S3; hb = h3; }
                else if (S2 >= rem) { bin = 4*l+2; Sb = S2; hb = h2; }
                else if (S1 >= rem) { bin = 4*l+1; Sb = S1; hb = h1; }
                else                { bin = 4*l+0; Sb = S0; hb = h0; }
                sKrem = (int)(rem - (Sb - hb));    // >= 1 by construction
                sPref = pv | ((uint32_t)bin << shift);
                sMask = pm | (0xFFu << shift);
            }
        }
        __syncthreads();
    }
    uint32_t T = sPref;
    int tiesNeeded = sKrem;            // >= 1
    if (threadIdx.x == 0) { gcnt = 0; tcnt = 0; }
    __syncthreads();

    #pragma unroll
    for (int s = 0; s < NSLOT_Q; ++s) {
        int i = threadIdx.x + (s << 8);
        uint32_t vb = kr[s];           // sentinel 0: never >T, never ==T
        if (vb > T) { int p = atomicAdd(&gcnt, 1); if (p < TOPK) cand[p] = make_uint2(vb, (uint32_t)sidx[i]); }
        else if (vb == T) { int p = atomicAdd(&tcnt, 1); if (p < 256) tieIdx[p] = (uint32_t)sidx[i]; }
    }
    __syncthreads();
    int g  = min(gcnt, TOPK);          // == TOPK - tiesNeeded by construction
    int tc = min(tcnt, 256);

    for (int i = threadIdx.x; i < 128; i += blockDim.x) keys[i] = 0;
    __syncthreads();
    // greater-than-threshold entries
    for (int i = threadIdx.x; i < g; i += blockDim.x)
        keys[i] = ((uint64_t)cand[i].x << 32) | (uint64_t)(0xFFFFFFFFu - cand[i].y);
    // tie entries: take the tiesNeeded smallest indices (jax lower-index-first)
    for (int i = threadIdx.x; i < tc; i += blockDim.x) {
        uint32_t my = tieIdx[i];
        int r = 0;
        for (int m2 = 0; m2 < tc; ++m2) r += (tieIdx[m2] < my) ? 1 : 0;
        if (r < tiesNeeded)
            keys[g + r] = ((uint64_t)T << 32) | (uint64_t)(0xFFFFFFFFu - my);
    }
    __syncthreads();

    // ---- phase 3: bitonic sort 128 keys desc (value desc, index asc) ----
    // exactly 100 nonzero keys (g + tiesNeeded == TOPK); zeros sink to the end.
    for (int len = 2; len <= 128; len <<= 1) {
        for (int stride = len >> 1; stride > 0; stride >>= 1) {
            int i = threadIdx.x;
            if (i < 128) {
                int j2 = i ^ stride;
                if (j2 > i) {
                    uint64_t a = keys[i], c2 = keys[j2];
                    bool desc = ((i & len) == 0);
                    bool sw = desc ? (a < c2) : (a > c2);
                    if (sw) { keys[i] = c2; keys[j2] = a; }
                }
            }
            __syncthreads();
        }
    }

    uint64_t* __restrict__ pk = part_keys + (size_t)bid * TOPK;
    for (int k = threadIdx.x; k < TOPK; k += blockDim.x) pk[k] = keys[k];
}

// decode tail: one block per (batch, joint) = 256 blocks, 128 threads.
// Prologue: exact 4-way rank-merge of the quarter top-100 lists for the det
// channel and this joint's channel (rank = own pos + binary-search counts in
// the other 3 sorted lists; composite keys unique -> ranks are a permutation,
// top-100 fills exactly). Deterministic across the 8 j-blocks that redundantly
// merge the det channel.
__global__ __launch_bounds__(128) void decode_tail(
                            const float* __restrict__ wh, const float* __restrict__ kps,
                            const float* __restrict__ reg, const float* __restrict__ scale,
                            const float* __restrict__ hp_offset,
                            const uint64_t* __restrict__ part_keys,
                            float* __restrict__ out) {
    int b = blockIdx.x >> 3;
    int j = blockIdx.x & 7;
    __shared__ uint64_t ldet[NPART * TOPK], ljnt[NPART * TOPK];  // 6400 B
    __shared__ uint64_t mdet[TOPK], mjnt[TOPK];                  // 1600 B
    __shared__ float sx[TOPK], sy[TOPK], ss[TOPK];
    __shared__ float skx[TOPK], sky[TOPK];
    __shared__ float sbb0[TOPK], sbb1[TOPK], sbb2[TOPK], sbb3[TOPK];
    __shared__ float ssc[TOPK];
    int t = threadIdx.x;
    int chd = b * NCHAN;               // det channel
    int chj = b * NCHAN + 1 + j;       // this joint's channel

    for (int i = t; i < NPART * TOPK; i += 128) {
        ldet[i] = part_keys[(size_t)chd * NPART * TOPK + i];
        ljnt[i] = part_keys[(size_t)chj * NPART * TOPK + i];
    }
    __syncthreads();
    for (int i = t; i < 2 * NPART * TOPK; i += 128) {
        bool isj = i >= NPART * TOPK;
        int ii = isj ? i - NPART * TOPK : i;
        const uint64_t* base = isj ? ljnt : ldet;
        int p = ii / TOPK, tt = ii % TOPK;
        uint64_t v = base[p * TOPK + tt];
        int rank = tt;
        #pragma unroll
        for (int qq = 0; qq < NPART; ++qq) {
            if (qq == p) continue;
            const uint64_t* L = base + qq * TOPK;
            int lo = 0, hi = TOPK;     // count of elements strictly > v (desc list)
            while (lo < hi) { int mid = (lo + hi) >> 1; if (L[mid] > v) lo = mid + 1; else hi = mid; }
            rank += lo;
        }
        if (rank < TOPK) { if (isj) mjnt[rank] = v; else mdet[rank] = v; }
    }
    __syncthreads();

    if (t < TOPK) {
        // heatmap keypoint candidates for this joint
        uint64_t jv = mjnt[t];
        int ind = (int)(0xFFFFFFFFu - (uint32_t)jv);
        float sc = sigmoidf_(key_to_float((uint32_t)(jv >> 32)));
        float x = (float)(ind & 255) + hp_offset[((size_t)b * 2 + 0) * HW + ind];
        float y = (float)(ind >> 8)  + hp_offset[((size_t)b * 2 + 1) * HW + ind];
        bool m = sc > THRESH_C;
        ss[t] = m ? sc : -1.0f;
        sx[t] = m ? x  : NEG_C;
        sy[t] = m ? y  : NEG_C;

        // det decode (bbox, score) + this joint's displacement
        int tid2 = b * TOPK + t;
        uint64_t dv = mdet[t];
        int dind = (int)(0xFFFFFFFFu - (uint32_t)dv);
        float sc2 = sigmoidf_(key_to_float((uint32_t)(dv >> 32)));
        float xs = (float)(dind & 255), ys = (float)(dind >> 8);
        float xr = xs + reg[((size_t)b * 2 + 0) * HW + dind];
        float yr = ys + reg[((size_t)b * 2 + 1) * HW + dind];
        float w0 = wh[((size_t)b * 2 + 0) * HW + dind];
        float w1 = wh[((size_t)b * 2 + 1) * HW + dind];
        float x0 = xr - w0 * 0.5f, y0 = yr - w1 * 0.5f;
        float x1 = xr + w0 * 0.5f, y1 = yr + w1 * 0.5f;
        sbb0[t] = x0; sbb1[t] = y0; sbb2[t] = x1; sbb3[t] = y1;
        ssc[t] = sc2;
        float kx = kps[((size_t)b * 16 + 2 * j)     * HW + dind] + xs;
        float ky = kps[((size_t)b * 16 + 2 * j + 1) * HW + dind] + ys;
        skx[t] = kx; sky[t] = ky;
        out[OUT_DISP + (size_t)tid2 * 16 + 2 * j]     = kx;
        out[OUT_DISP + (size_t)tid2 * 16 + 2 * j + 1] = ky;
        if (j == 0) {
            float* bb = out + OUT_BBOX + (size_t)tid2 * 4;
            bb[0] = x0; bb[1] = y0; bb[2] = x1; bb[3] = y1;
            out[OUT_SCORE + tid2] = sc2;
            out[OUT_CLS + tid2] = 0.0f;   // clses = ind // K over c=1 -> always 0
            float* os = out + OUT_SCALE + (size_t)tid2 * 3;
            os[0] = scale[((size_t)b * 3 + 0) * HW + dind];
            os[1] = scale[((size_t)b * 3 + 1) * HW + dind];
            os[2] = scale[((size_t)b * 3 + 2) * HW + dind];
        }
    }
    __syncthreads();
    if (t < TOPK) {
        float kx = skx[t], ky = sky[t];
        float best = 1e30f; int bl = 0;
        for (int l = 0; l < TOPK; ++l) {
            float dx = kx - sx[l];
            float dy = ky - sy[l];
            float dist = sqrtf(dx * dx + dy * dy);
            if (dist < best) { best = dist; bl = l; }  // strict <: first-min == argmin
        }
        float hx = sx[bl], hy = sy[bl], hs = ss[bl];
        float x0 = sbb0[t], y0 = sbb1[t], x1 = sbb2[t], y1 = sbb3[t];
        float diag = fmaxf(y1 - y0, x1 - x0);
        int tid2 = b * TOPK + t;
        bool mask = (hx < x0) || (hx > x1) || (hy < y0) || (hy > y1) ||
                    (hs < THRESH_C) || (best > diag * 0.3f);
        out[OUT_KPS + (size_t)tid2 * 16 + 2 * j]     = mask ? kx : hx;
        out[OUT_KPS + (size_t)tid2 * 16 + 2 * j + 1] = mask ? ky : hy;
        float sc = ssc[t];
        bool mask2 = (hx > 0.8f * x0) && (hx < 1.2f * x1) && (hy > 0.8f * y0) &&
                     (hy < 1.2f * y1) && (hs > THRESH_C) && (best < diag * 0.5f) &&
                     (sc > THRESH_C);
        float fx = mask2 ? hx : NEG_C;
        float fy = mask2 ? hy : NEG_C;
        bool valid = (fx != NEG_C) && (fy != NEG_C);
        out[OUT_HEAT + (size_t)tid2 * 16 + 2 * j]     = valid ? fx : NEG_C;
        out[OUT_HEAT + (size_t)tid2 * 16 + 2 * j + 1] = valid ? fy : NEG_C;
    }
}

extern "C" void kernel_launch(void* const* d_in, const int* in_sizes, int n_in,
                              void* d_out, int out_size, void* d_ws, size_t ws_size,
                              hipStream_t stream) {
    const float* hm        = (const float*)d_in[0];
    const float* wh        = (const float*)d_in[1];
    const float* kps       = (const float*)d_in[2];
    const float* reg       = (const float*)d_in[3];
    const float* hm_hp     = (const float*)d_in[4];
    const float* hp_offset = (const float*)d_in[5];
    const float* scale     = (const float*)d_in[6];
    float* out = (float*)d_out;
    char* ws = (char*)d_ws;

    // workspace: per-quarter sorted top-100 composite keys
    uint64_t* part_keys = (uint64_t*)ws;   // 1152 * 100 * 8 = 921600 B

    nms_topk<<<NCH * NPART, 256, 0, stream>>>(hm, hm_hp, part_keys);
    decode_tail<<<NB * NJ, 128, 0, stream>>>(wh, kps, reg, scale, hp_offset,
                                             part_keys, out);
}

// Round 4
// 285.708 us; speedup vs baseline: 1.0227x; 1.0227x over previous
//
#include <hip/hip_runtime.h>
#include <stdint.h>
#include <math.h>

// ---- problem constants ----
#define NB 32
#define NH 256
#define NW 256
#define HW 65536
#define NJ 8
#define NCHAN 9           // 1 det channel + 8 joint channels per batch
#define NCH 288           // NB * NCHAN
#define TOPK 100
#define THRESH_C 0.1f
#define NEG_C (-10000.0f)
#define SEG 1152          // per-wave survivor segment; mean ~910, sigma ~28 -> mu+8.6sigma
#define CAPS (8 * SEG)    // 9216 total staged survivors (zero-padded gaps)
#define NSLOT 18          // CAPS / 512 register key slots per thread

// ---- output layout (float offsets), concat of reference return tuple ----
#define OUT_BBOX  0       // (32,100,4)   12800
#define OUT_SCORE 12800   // (32,100,1)    3200
#define OUT_KPS   16000   // (32,100,16)  51200
#define OUT_CLS   67200   // (32,100,1)    3200
#define OUT_SCALE 70400   // (32,100,3)    9600
#define OUT_DISP  80000   // (32,100,16)  51200
#define OUT_HEAT  131200  // (32,100,16)  51200
// total 182400

// monotone float->uint key (order-preserving, incl. negatives)
__device__ __forceinline__ uint32_t flip_key(uint32_t b) {
    return (b & 0x80000000u) ? ~b : (b | 0x80000000u);
}
__device__ __forceinline__ float key_to_float(uint32_t k) {
    uint32_t b = (k & 0x80000000u) ? (k & 0x7FFFFFFFu) : ~k;
    return __uint_as_float(b);
}
__device__ __forceinline__ float sigmoidf_(float x) {
    return 1.0f / (1.0f + expf(-x));
}

// Fused NMS + survivor compaction + exact per-channel top-K.
// One block per channel (288 blocks, 512 threads = 8 waves), 2 blocks/CU
// resident (LDS ~67 KB). R3 lesson: grid imbalance is irrelevant at low
// utilization (co-resident blocks overlap); the lever is the single-block
// critical path. This version cuts it: per-wave survivor segments (no
// cross-wave atomic, readfirstlane broadcast), 8 privatized histograms
// (hot-bin serialization /2), rank-placement epilogue instead of a 28-barrier
// bitonic sort, depth-3 prefetch in the stream phase.
__global__ __launch_bounds__(512, 4) void nms_topk(
        const float* __restrict__ hm, const float* __restrict__ hm_hp,
        float* __restrict__ det_score, int* __restrict__ det_ind,
        float* __restrict__ hp_score, int* __restrict__ hp_ind) {
    int ch = blockIdx.x;
    int b = ch / NCHAN, c = ch % NCHAN;
    const float* __restrict__ src = (c == 0)
        ? (hm + (size_t)b * HW)
        : (hm_hp + ((size_t)b * NJ + (c - 1)) * HW);

    __shared__ uint32_t skey[CAPS];      // 36864 B survivor keys (flip-float), 0 = gap sentinel
    __shared__ uint16_t sidx[CAPS];      // 18432 B survivor pixel index (y*256+x)
    __shared__ uint32_t hist[8 * 257];   // 8224 B  one copy per wave, 257-pitch de-aliases banks
    __shared__ uint2 cand[TOPK];         // 800 B
    __shared__ uint32_t tieIdx[256];     // 1024 B
    __shared__ uint64_t w100[TOPK];      // 800 B   final 100 composite keys (unordered)
    __shared__ uint32_t wcnt[8 * 17];    // 544 B   per-wave survivor counters (bank-spread)
    __shared__ int sKrem;
    __shared__ uint32_t sMask, sPref;
    __shared__ int gcnt, tcnt;
    // total ~66.7 KB -> 2 blocks/CU

    int w    = threadIdx.x >> 6;        // wave 0..7: rows [32w, 32w+32)
    int lane = threadIdx.x & 63;        // 64 col-groups of 4 px (float4)
    if (lane == 0) wcnt[w * 17] = 0;
    __syncthreads();

    // ---- phase 1: streamed NMS (RAW space, monotone-equiv to sigmoid) ----
    // 8 waves x 32 rows, depth-3 rolling prefetch.
    int y0 = w * 32;
    int xb = lane * 4;
    const float4* __restrict__ rbase = (const float4*)src;  // row r: rbase[r*64+lane]

    float4 prev = rbase[(size_t)((y0 > 0) ? y0 - 1 : 0) * 64 + lane];
    float4 cur  = rbase[(size_t)y0 * 64 + lane];
    float4 nxt  = rbase[(size_t)(y0 + 1) * 64 + lane];   // y0 <= 224 -> <= 225
    float4 nxt2 = rbase[(size_t)(y0 + 2) * 64 + lane];   // <= 226
    float4 nxt3 = rbase[(size_t)(y0 + 3) * 64 + lane];   // <= 227

    int segEnd = (w + 1) * SEG;
    for (int y = y0; y < y0 + 32; ++y) {
        int ypf = y + 4; if (ypf > NH - 1) ypf = NH - 1;
        float4 nxt4 = rbase[(size_t)ypf * 64 + lane];    // prefetch (used in 3 iters)

        float4 nb;                                        // row y+1 (clamped)
        if (y < NH - 1) nb = nxt; else nb = cur;

        // vertical max per column
        float vm0 = fmaxf(fmaxf(prev.x, cur.x), nb.x);
        float vm1 = fmaxf(fmaxf(prev.y, cur.y), nb.y);
        float vm2 = fmaxf(fmaxf(prev.z, cur.z), nb.z);
        float vm3 = fmaxf(fmaxf(prev.w, cur.w), nb.w);

        // horizontal edges from neighbor lanes (one wave == one row)
        float fromLeft  = __shfl(vm3, (lane + 63) & 63);
        float fromRight = __shfl(vm0, (lane + 1) & 63);
        if (lane == 0)  fromLeft  = vm0;   // x=0 clamps to itself
        if (lane == 63) fromRight = vm3;   // x=255 clamps to itself

        float h0 = fmaxf(fromLeft, fmaxf(vm0, vm1));
        float h1 = fmaxf(vm0, fmaxf(vm1, vm2));
        float h2 = fmaxf(vm1, fmaxf(vm2, vm3));
        float h3 = fmaxf(vm2, fmaxf(vm3, fromRight));

        bool s0 = (cur.x >= h0), s1 = (cur.y >= h1);
        bool s2 = (cur.z >= h2), s3 = (cur.w >= h3);

        // ballot-ranked append into this wave's private segment
        uint64_t b0 = __ballot(s0), b1 = __ballot(s1);
        uint64_t b2 = __ballot(s2), b3 = __ballot(s3);
        int n0 = __popcll(b0), n1 = __popcll(b1);
        int n2 = __popcll(b2), n3 = __popcll(b3);
        int wtot = n0 + n1 + n2 + n3;
        uint64_t mlt = ((uint64_t)1 << lane) - 1;
        int r0 = __popcll(b0 & mlt);
        int r1 = n0 + __popcll(b1 & mlt);
        int r2 = n0 + n1 + __popcll(b2 & mlt);
        int r3 = n0 + n1 + n2 + __popcll(b3 & mlt);
        int wbase_l = 0;
        if (lane == 0) wbase_l = atomicAdd(&wcnt[w * 17], (uint32_t)wtot);
        int wbase = w * SEG + __builtin_amdgcn_readfirstlane(wbase_l);  // SALU broadcast

        int rowoff = y * NW + xb;
        if (s0) { int o = wbase + r0; if (o < segEnd) { skey[o] = flip_key(__float_as_uint(cur.x)); sidx[o] = (uint16_t)(rowoff + 0); } }
        if (s1) { int o = wbase + r1; if (o < segEnd) { skey[o] = flip_key(__float_as_uint(cur.y)); sidx[o] = (uint16_t)(rowoff + 1); } }
        if (s2) { int o = wbase + r2; if (o < segEnd) { skey[o] = flip_key(__float_as_uint(cur.z)); sidx[o] = (uint16_t)(rowoff + 2); } }
        if (s3) { int o = wbase + r3; if (o < segEnd) { skey[o] = flip_key(__float_as_uint(cur.w)); sidx[o] = (uint16_t)(rowoff + 3); } }

        prev = cur; cur = nxt; nxt = nxt2; nxt2 = nxt3; nxt3 = nxt4;
    }

    __syncthreads();
    // zero-fill segment gaps so select runs over fixed CAPS with sentinel 0
    // (flip_key of a real value is never 0; sentinel never matches any pass)
    for (int i = threadIdx.x; i < CAPS; i += 512) {
        int seg = i / SEG;                  // magic-mul, cheap
        uint32_t cnt = wcnt[seg * 17];
        if ((uint32_t)(i - seg * SEG) >= cnt) skey[i] = 0u;
    }
    __syncthreads();

    // stage keys into registers once (static slots, fully unrolled -> no scratch)
    uint32_t kr[NSLOT];
    #pragma unroll
    for (int s = 0; s < NSLOT; ++s) kr[s] = skey[threadIdx.x + (s << 9)];

    // ---- phase 2: byte-radix select of exact top-K threshold ----
    if (threadIdx.x == 0) { sKrem = TOPK; sMask = 0; sPref = 0; }
    uint32_t* hmine = &hist[w * 257];    // private histogram copy per wave
    for (int shift = 24; shift >= 0; shift -= 8) {
        for (int i = threadIdx.x; i < 8 * 257; i += 512) hist[i] = 0;
        __syncthreads();
        uint32_t pm = sMask, pv = sPref;
        #pragma unroll
        for (int s = 0; s < NSLOT; ++s) {
            uint32_t vb = kr[s];
            if (vb != 0u && (vb & pm) == pv)
                atomicAdd(&hmine[(vb >> shift) & 0xFF], 1u);
        }
        __syncthreads();
        // wave-0 parallel threshold scan: merge 8 copies, shfl suffix-sum,
        // locate largest bin with suffix >= rem.
        if (threadIdx.x < 64) {
            int l = threadIdx.x;
            uint32_t h0 = 0, h1 = 0, h2 = 0, h3 = 0;
            #pragma unroll
            for (int cc = 0; cc < 8; ++cc) {
                h0 += hist[cc * 257 + 4 * l + 0];
                h1 += hist[cc * 257 + 4 * l + 1];
                h2 += hist[cc * 257 + 4 * l + 2];
                h3 += hist[cc * 257 + 4 * l + 3];
            }
            uint32_t loc = h0 + h1 + h2 + h3;
            uint32_t suf = loc;                    // suffix sum over lanes >= l
            #pragma unroll
            for (int d = 1; d < 64; d <<= 1) {
                uint32_t o = __shfl_down(suf, d, 64);
                suf += (l + d < 64) ? o : 0u;
            }
            uint32_t above = suf - loc;            // sum over lanes > l
            uint32_t rem = (uint32_t)sKrem;        // all lanes read before boundary lane writes
            if (suf >= rem && above < rem) {       // unique lane holds the boundary
                uint32_t S3 = above + h3;
                uint32_t S2 = S3 + h2;
                uint32_t S1 = S2 + h1;
                uint32_t S0 = S1 + h0;             // == suf
                int bin; uint32_t Sb, hb;
                if      (S3 >= rem) { bin = 4*l+3; Sb = S3; hb = h3; }
                else if (S2 >= rem) { bin = 4*l+2; Sb = S2; hb = h2; }
                else if (S1 >= rem) { bin = 4*l+1; Sb = S1; hb = h1; }
                else                { bin = 4*l+0; Sb = S0; hb = h0; }
                sKrem = (int)(rem - (Sb - hb));    // >= 1 by construction
                sPref = pv | ((uint32_t)bin << shift);
                sMask = pm | (0xFFu << shift);
            }
        }
        __syncthreads();
    }
    uint32_t T = sPref;
    int tiesNeeded = sKrem;            // >= 1
    if (threadIdx.x == 0) { gcnt = 0; tcnt = 0; }
    __syncthreads();

    #pragma unroll
    for (int s = 0; s < NSLOT; ++s) {
        int i = threadIdx.x + (s << 9);
        uint32_t vb = kr[s];           // sentinel 0: never >T, never ==T (T >= 0x80000000)
        if (vb > T) { int p = atomicAdd(&gcnt, 1); if (p < TOPK) cand[p] = make_uint2(vb, (uint32_t)sidx[i]); }
        else if (vb == T) { int p = atomicAdd(&tcnt, 1); if (p < 256) tieIdx[p] = (uint32_t)sidx[i]; }
    }
    __syncthreads();
    int g  = min(gcnt, TOPK);          // == TOPK - tiesNeeded by construction
    int tc = min(tcnt, 256);

    // build the 100 winner composites (unordered); composite = value desc, index asc
    for (int i = threadIdx.x; i < g; i += blockDim.x)
        w100[i] = ((uint64_t)cand[i].x << 32) | (uint64_t)(0xFFFFFFFFu - cand[i].y);
    // tie entries: take the tiesNeeded smallest indices (jax lower-index-first)
    for (int i = threadIdx.x; i < tc; i += blockDim.x) {
        uint32_t my = tieIdx[i];
        int r = 0;
        for (int m2 = 0; m2 < tc; ++m2) r += (tieIdx[m2] < my) ? 1 : 0;
        if (r < tiesNeeded)
            w100[g + r] = ((uint64_t)T << 32) | (uint64_t)(0xFFFFFFFFu - my);
    }
    __syncthreads();

    // ---- phase 3: rank-placement (no bitonic, no extra barriers) ----
    // 100 unique u64 keys -> rank = #greater; scatter output at rank.
    if (threadIdx.x < TOPK) {
        uint64_t v = w100[threadIdx.x];
        int rank = 0;
        for (int j2 = 0; j2 < TOPK; ++j2) rank += (w100[j2] > v) ? 1 : 0;  // broadcast reads
        float raw = key_to_float((uint32_t)(v >> 32));
        int idx = (int)(0xFFFFFFFFu - (uint32_t)v);
        float s = sigmoidf_(raw);
        if (c == 0) { det_score[b * TOPK + rank] = s; det_ind[b * TOPK + rank] = idx; }
        else {
            int o = (b * NJ + (c - 1)) * TOPK + rank;
            hp_score[o] = s; hp_ind[o] = idx;
        }
    }
}

// decode tail: one block per (batch, joint) = 256 blocks, 128 threads.
// Per-b det work (bbox/score/scale) recomputed per j-block (tiny);
// only the j==0 block writes the shared det outputs.
__global__ __launch_bounds__(128) void decode_tail(
                            const float* __restrict__ wh, const float* __restrict__ kps,
                            const float* __restrict__ reg, const float* __restrict__ scale,
                            const float* __restrict__ hp_offset,
                            const float* __restrict__ det_score, const int* __restrict__ det_ind,
                            const float* __restrict__ hp_score, const int* __restrict__ hp_ind,
                            float* __restrict__ out) {
    int b = blockIdx.x >> 3;
    int j = blockIdx.x & 7;
    __shared__ float sx[TOPK], sy[TOPK], ss[TOPK];
    __shared__ float skx[TOPK], sky[TOPK];
    __shared__ float sbb0[TOPK], sbb1[TOPK], sbb2[TOPK], sbb3[TOPK];
    __shared__ float ssc[TOPK];
    int t = threadIdx.x;
    if (t < TOPK) {
        // heatmap keypoint candidates for this joint
        int o = (b * NJ + j) * TOPK + t;
        int ind = hp_ind[o];
        float sc = hp_score[o];
        float x = (float)(ind & 255) + hp_offset[((size_t)b * 2 + 0) * HW + ind];
        float y = (float)(ind >> 8)  + hp_offset[((size_t)b * 2 + 1) * HW + ind];
        bool m = sc > THRESH_C;
        ss[t] = m ? sc : -1.0f;
        sx[t] = m ? x  : NEG_C;
        sy[t] = m ? y  : NEG_C;

        // det decode (bbox, score) + this joint's displacement
        int tid2 = b * TOPK + t;
        int dind = det_ind[tid2];
        float xs = (float)(dind & 255), ys = (float)(dind >> 8);
        float xr = xs + reg[((size_t)b * 2 + 0) * HW + dind];
        float yr = ys + reg[((size_t)b * 2 + 1) * HW + dind];
        float w0 = wh[((size_t)b * 2 + 0) * HW + dind];
        float w1 = wh[((size_t)b * 2 + 1) * HW + dind];
        float x0 = xr - w0 * 0.5f, y0 = yr - w1 * 0.5f;
        float x1 = xr + w0 * 0.5f, y1 = yr + w1 * 0.5f;
        sbb0[t] = x0; sbb1[t] = y0; sbb2[t] = x1; sbb3[t] = y1;
        float sc2 = det_score[tid2];
        ssc[t] = sc2;
        float kx = kps[((size_t)b * 16 + 2 * j)     * HW + dind] + xs;
        float ky = kps[((size_t)b * 16 + 2 * j + 1) * HW + dind] + ys;
        skx[t] = kx; sky[t] = ky;
        out[OUT_DISP + (size_t)tid2 * 16 + 2 * j]     = kx;
        out[OUT_DISP + (size_t)tid2 * 16 + 2 * j + 1] = ky;
        if (j == 0) {
            float* bb = out + OUT_BBOX + (size_t)tid2 * 4;
            bb[0] = x0; bb[1] = y0; bb[2] = x1; bb[3] = y1;
            out[OUT_SCORE + tid2] = sc2;
            out[OUT_CLS + tid2] = 0.0f;   // clses = ind // K over c=1 -> always 0
            float* os = out + OUT_SCALE + (size_t)tid2 * 3;
            os[0] = scale[((size_t)b * 3 + 0) * HW + dind];
            os[1] = scale[((size_t)b * 3 + 1) * HW + dind];
            os[2] = scale[((size_t)b * 3 + 2) * HW + dind];
        }
    }
    __syncthreads();
    if (t < TOPK) {
        float kx = skx[t], ky = sky[t];
        float best = 1e30f; int bl = 0;
        for (int l = 0; l < TOPK; ++l) {
            float dx = kx - sx[l];
            float dy = ky - sy[l];
            float dist = sqrtf(dx * dx + dy * dy);
            if (dist < best) { best = dist; bl = l; }  // strict <: first-min == argmin
        }
        float hx = sx[bl], hy = sy[bl], hs = ss[bl];
        float x0 = sbb0[t], y0 = sbb1[t], x1 = sbb2[t], y1 = sbb3[t];
        float diag = fmaxf(y1 - y0, x1 - x0);
        int tid2 = b * TOPK + t;
        bool mask = (hx < x0) || (hx > x1) || (hy < y0) || (hy > y1) ||
                    (hs < THRESH_C) || (best > diag * 0.3f);
        out[OUT_KPS + (size_t)tid2 * 16 + 2 * j]     = mask ? kx : hx;
        out[OUT_KPS + (size_t)tid2 * 16 + 2 * j + 1] = mask ? ky : hy;
        float sc = ssc[t];
        bool mask2 = (hx > 0.8f * x0) && (hx < 1.2f * x1) && (hy > 0.8f * y0) &&
                     (hy < 1.2f * y1) && (hs > THRESH_C) && (best < diag * 0.5f) &&
                     (sc > THRESH_C);
        float fx = mask2 ? hx : NEG_C;
        float fy = mask2 ? hy : NEG_C;
        bool valid = (fx != NEG_C) && (fy != NEG_C);
        out[OUT_HEAT + (size_t)tid2 * 16 + 2 * j]     = valid ? fx : NEG_C;
        out[OUT_HEAT + (size_t)tid2 * 16 + 2 * j + 1] = valid ? fy : NEG_C;
    }
}

extern "C" void kernel_launch(void* const* d_in, const int* in_sizes, int n_in,
                              void* d_out, int out_size, void* d_ws, size_t ws_size,
                              hipStream_t stream) {
    const float* hm        = (const float*)d_in[0];
    const float* wh        = (const float*)d_in[1];
    const float* kps       = (const float*)d_in[2];
    const float* reg       = (const float*)d_in[3];
    const float* hm_hp     = (const float*)d_in[4];
    const float* hp_offset = (const float*)d_in[5];
    const float* scale     = (const float*)d_in[6];
    float* out = (float*)d_out;
    char* ws = (char*)d_ws;

    // workspace layout (bytes) -- no survivor buffer, no counters, no memset
    float* det_score = (float*)(ws);                     // 3200 f   = 12800 B
    int*   det_ind   = (int*)(ws + 12800);               // 3200 i   = 12800 B
    float* hp_score  = (float*)(ws + 25600);             // 25600 f  = 102400 B
    int*   hp_ind    = (int*)(ws + 128000);              // 25600 i  = 102400 B
    // total 230400 B

    nms_topk<<<NCH, 512, 0, stream>>>(hm, hm_hp, det_score, det_ind, hp_score, hp_ind);
    decode_tail<<<NB * NJ, 128, 0, stream>>>(wh, kps, reg, scale, hp_offset,
                                             det_score, det_ind, hp_score, hp_ind, out);
}